// Round 3
// baseline (89.794 us; speedup 1.0000x reference)
//
#include <hip/hip_runtime.h>
#include <stdint.h>

#define MARGIN 0.3f
#define NROWS 4096
#define DIM   2048
#define BT    128
#define BK    64
#define NK    (DIM / BK)            // 32
#define NB    (NROWS / BT)          // 32
#define NBLK  (NB * (NB + 1) / 2)   // 528

typedef float f32x4 __attribute__((ext_vector_type(4)));
typedef short s16x8 __attribute__((ext_vector_type(8)));

#define WAITV8() asm volatile("s_waitcnt vmcnt(8)" ::: "memory")
#define WAITV0() asm volatile("s_waitcnt vmcnt(0)" ::: "memory")
#define WAITL0() asm volatile("s_waitcnt lgkmcnt(0)" ::: "memory")
#define BAR()    __builtin_amdgcn_s_barrier()
#define SCHED0() __builtin_amdgcn_sched_barrier(0)

__device__ __forceinline__ ushort f32_to_bf16(float f) {
  uint32_t u = __float_as_uint(f);
  return (ushort)((u + 0x7FFFu + ((u >> 16) & 1u)) >> 16);  // RNE, no NaN in data
}

// async global->LDS, 16B per lane. LDS dest is wave-uniform base + lane*16
// (linear). The k-slot XOR swizzle is carried on the GLOBAL source address.
__device__ __forceinline__ void async_load16(const ushort* g, ushort* l) {
  __builtin_amdgcn_global_load_lds(
      (const __attribute__((address_space(1))) uint32_t*)g,
      (__attribute__((address_space(3))) uint32_t*)l, 16, 0, 0);
}

// ---------------------------------------------------------------------------
// prep: row L2-norm. FLY=0: write normalized bf16 matrix. FLY=1: write 1/norm.
// Also zeroes the accumulators (block 0, thread 0).
// ---------------------------------------------------------------------------
template <int FLY>
__global__ __launch_bounds__(256) void prep_kernel(const float* __restrict__ in,
                                                   ushort* __restrict__ pn,
                                                   float* __restrict__ invn,
                                                   float* __restrict__ accum) {
  const int row = blockIdx.x;
  const int tid = threadIdx.x;
  if (row == 0 && tid == 0) { accum[0] = 0.f; accum[1] = 0.f; }

  const float4* rp = (const float4*)(in + (size_t)row * DIM);
  float4 v0 = rp[tid * 2];
  float4 v1 = rp[tid * 2 + 1];
  float ss = v0.x*v0.x + v0.y*v0.y + v0.z*v0.z + v0.w*v0.w
           + v1.x*v1.x + v1.y*v1.y + v1.z*v1.z + v1.w*v1.w;
  #pragma unroll
  for (int off = 32; off; off >>= 1) ss += __shfl_down(ss, off);

  __shared__ float wred[4];
  __shared__ float stot;
  const int lane = tid & 63, w = tid >> 6;
  if (lane == 0) wred[w] = ss;
  __syncthreads();
  if (tid == 0) stot = wred[0] + wred[1] + wred[2] + wred[3];
  __syncthreads();
  const float inv = 1.0f / fmaxf(sqrtf(stot), 1e-12f);

  if (FLY) {
    if (tid == 0) invn[row] = inv;
  } else {
    int4 pack;
    ushort* h = (ushort*)&pack;
    h[0] = f32_to_bf16(v0.x * inv); h[1] = f32_to_bf16(v0.y * inv);
    h[2] = f32_to_bf16(v0.z * inv); h[3] = f32_to_bf16(v0.w * inv);
    h[4] = f32_to_bf16(v1.x * inv); h[5] = f32_to_bf16(v1.y * inv);
    h[6] = f32_to_bf16(v1.z * inv); h[7] = f32_to_bf16(v1.w * inv);
    *(int4*)(pn + (size_t)row * DIM + tid * 8) = pack;
  }
}

// ---------------------------------------------------------------------------
// tri_gemm: one block per upper-triangular 128x128 super-tile of sim = Pn Pn^T.
// 4 waves (2x2), each wave a 64x64 sub-tile as 4x4 fragments of 16x16x32 MFMA,
// BK=64 K-steps, double-buffered LDS, counted vmcnt(8) across raw s_barriers
// (T3/T4-lite): next tile's global_load_lds stay in flight through the
// barrier, so no vmcnt(0) drain in the main loop.
// ---------------------------------------------------------------------------

__device__ __forceinline__ void stage_tiles(const ushort* __restrict__ pn,
                                            int rowA, int rowB, int k0,
                                            ushort* Abuf, ushort* Bbuf,
                                            int w, int srow, int gslot) {
  // 1 KB chunk = 8 rows x 128 B; lane l -> row +(l>>3), stored slot (l&7);
  // global true-k slot = (l&7) ^ (l>>3)  [row&7 == l>>3]
  #pragma unroll
  for (int q = 0; q < 4; ++q) {
    const int r = w * 32 + q * 8;
    async_load16(pn + (size_t)(rowA + r + srow) * DIM + k0 + gslot * 8, Abuf + r * BK);
    async_load16(pn + (size_t)(rowB + r + srow) * DIM + k0 + gslot * 8, Bbuf + r * BK);
  }
}

__device__ __forceinline__ void compute_step(const ushort* Abuf, const ushort* Bbuf,
                                             int wr, int wc, int lane,
                                             f32x4 acc[4][4]) {
  s16x8 af[2][4], bfv[2][4];
  const int fr = lane & 15, hi = lane >> 4;
  #pragma unroll
  for (int kk = 0; kk < 2; ++kk) {
    #pragma unroll
    for (int m = 0; m < 4; ++m) {
      const int ra = wr * 64 + m * 16 + fr;
      af[kk][m] = *(const s16x8*)(Abuf + ra * BK + ((kk * 4 + hi) ^ (ra & 7)) * 8);
      const int rb = wc * 64 + m * 16 + fr;
      bfv[kk][m] = *(const s16x8*)(Bbuf + rb * BK + ((kk * 4 + hi) ^ (rb & 7)) * 8);
    }
  }
  #pragma unroll
  for (int kk = 0; kk < 2; ++kk)
    #pragma unroll
    for (int m = 0; m < 4; ++m)
      #pragma unroll
      for (int n = 0; n < 4; ++n)
        acc[m][n] = __builtin_amdgcn_mfma_f32_16x16x32_bf16(af[kk][m], bfv[kk][n],
                                                            acc[m][n], 0, 0, 0);
}

__global__ __launch_bounds__(256) void tri_gemm(const ushort* __restrict__ pn,
                                                float* __restrict__ accum) {
  int t = blockIdx.x, bi = 0;
  while (t >= NB - bi) { t -= NB - bi; ++bi; }
  const int bj = bi + t;

  __shared__ __align__(16) ushort Asm[2][BT * BK];   // 2 x 16 KB
  __shared__ __align__(16) ushort Bsm[2][BT * BK];   // 2 x 16 KB

  const int tid  = threadIdx.x;
  const int lane = tid & 63;
  const int w    = tid >> 6;
  const int wr   = w >> 1, wc = w & 1;
  const int srow  = (lane >> 3);
  const int gslot = (lane & 7) ^ srow;

  f32x4 acc[4][4] = {};
  const int rowA = bi * BT, rowB = bj * BT;

  stage_tiles(pn, rowA, rowB, 0, Asm[0], Bsm[0], w, srow, gslot);

  #pragma unroll 1
  for (int ks = 0; ks < NK - 2; ks += 2) {
    stage_tiles(pn, rowA, rowB, (ks + 1) * BK, Asm[1], Bsm[1], w, srow, gslot);
    WAITV8(); BAR(); SCHED0();
    compute_step(Asm[0], Bsm[0], wr, wc, lane, acc);
    WAITL0(); SCHED0(); BAR();

    stage_tiles(pn, rowA, rowB, (ks + 2) * BK, Asm[0], Bsm[0], w, srow, gslot);
    WAITV8(); BAR(); SCHED0();
    compute_step(Asm[1], Bsm[1], wr, wc, lane, acc);
    WAITL0(); SCHED0(); BAR();
  }
  // K-step NK-2: buffer 0 holds it (staged at end of last iteration)
  stage_tiles(pn, rowA, rowB, (NK - 1) * BK, Asm[1], Bsm[1], w, srow, gslot);
  WAITV8(); BAR(); SCHED0();
  compute_step(Asm[0], Bsm[0], wr, wc, lane, acc);
  WAITL0(); SCHED0(); BAR();
  // K-step NK-1
  WAITV0(); BAR(); SCHED0();
  compute_step(Asm[1], Bsm[1], wr, wc, lane, acc);

  // ---- epilogue: mask + reduce ----
  float lsum = 0.f, lcnt = 0.f;
  const int gib = rowA + wr * 64;
  const int gjb = rowB + wc * 64;
  #pragma unroll
  for (int m = 0; m < 4; ++m) {
    #pragma unroll
    for (int n = 0; n < 4; ++n) {
      #pragma unroll
      for (int r = 0; r < 4; ++r) {
        int gi = gib + m * 16 + (lane >> 4) * 4 + r;
        int gj = gjb + n * 16 + (lane & 15);
        float s = acc[m][n][r];
        if (gi < gj && s > MARGIN) { lsum += s - MARGIN; lcnt += 1.f; }
      }
    }
  }
  #pragma unroll
  for (int off = 32; off; off >>= 1) {
    lsum += __shfl_down(lsum, off);
    lcnt += __shfl_down(lcnt, off);
  }
  __shared__ float rs[4], rc[4];
  if (lane == 0) { rs[w] = lsum; rc[w] = lcnt; }
  __syncthreads();
  if (tid == 0) {
    atomicAdd(&accum[0], rs[0] + rs[1] + rs[2] + rs[3]);
    atomicAdd(&accum[1], rc[0] + rc[1] + rc[2] + rc[3]);
  }
}

// ---------------------------------------------------------------------------
// Fallback (tiny workspace): old single-buffer structure, on-the-fly convert.
// ---------------------------------------------------------------------------
__global__ __launch_bounds__(256) void tri_gemm_fly(const float* __restrict__ inF,
                                                    const float* __restrict__ invn,
                                                    float* __restrict__ accum) {
  int t = blockIdx.x, bi = 0;
  while (t >= NB - bi) { t -= NB - bi; ++bi; }
  const int bj = bi + t;

  __shared__ __align__(16) ushort Asm[BT * BK];
  __shared__ __align__(16) ushort Bsm[BT * BK];

  const int tid  = threadIdx.x;
  const int lane = tid & 63;
  const int w    = tid >> 6;
  const int wr   = w >> 1, wc = w & 1;

  f32x4 acc[4][4] = {};
  const int rowA = bi * BT, rowB = bj * BT;

  for (int k0 = 0; k0 < DIM; k0 += BK) {
    if (k0) __syncthreads();
    #pragma unroll
    for (int p = 0; p < 8; ++p) {
      int c   = p * 256 + tid;
      int isB = c >> 10;
      int cc  = c & 1023;
      int r   = cc >> 3;
      int s   = cc & 7;
      const int grow = (isB ? rowB : rowA) + r;
      const float4* src = (const float4*)(inF + (size_t)grow * DIM + k0 + s * 8);
      float4 v0 = src[0], v1 = src[1];
      int4 pack;
      ushort* h = (ushort*)&pack;
      h[0] = f32_to_bf16(v0.x); h[1] = f32_to_bf16(v0.y);
      h[2] = f32_to_bf16(v0.z); h[3] = f32_to_bf16(v0.w);
      h[4] = f32_to_bf16(v1.x); h[5] = f32_to_bf16(v1.y);
      h[6] = f32_to_bf16(v1.z); h[7] = f32_to_bf16(v1.w);
      *(int4*)((isB ? Bsm : Asm) + r * BK + (s ^ (r & 7)) * 8) = pack;
    }
    __syncthreads();
    compute_step(Asm, Bsm, wr, wc, lane, acc);
  }

  float lsum = 0.f, lcnt = 0.f;
  const int gib = rowA + wr * 64;
  const int gjb = rowB + wc * 64;
  #pragma unroll
  for (int m = 0; m < 4; ++m)
    #pragma unroll
    for (int n = 0; n < 4; ++n)
      #pragma unroll
      for (int r = 0; r < 4; ++r) {
        int gi = gib + m * 16 + (lane >> 4) * 4 + r;
        int gj = gjb + n * 16 + (lane & 15);
        float s = acc[m][n][r] * invn[gi] * invn[gj];
        if (gi < gj && s > MARGIN) { lsum += s - MARGIN; lcnt += 1.f; }
      }
  #pragma unroll
  for (int off = 32; off; off >>= 1) {
    lsum += __shfl_down(lsum, off);
    lcnt += __shfl_down(lcnt, off);
  }
  __shared__ float rs[4], rc[4];
  if (lane == 0) { rs[w] = lsum; rc[w] = lcnt; }
  __syncthreads();
  if (tid == 0) {
    atomicAdd(&accum[0], rs[0] + rs[1] + rs[2] + rs[3]);
    atomicAdd(&accum[1], rc[0] + rc[1] + rc[2] + rc[3]);
  }
}

__global__ void finalize_kernel(const float* __restrict__ accum, float* __restrict__ out) {
  if (threadIdx.x == 0) out[0] = (accum[1] < 0.5f) ? 0.0f : accum[0] / accum[1];
}

extern "C" void kernel_launch(void* const* d_in, const int* in_sizes, int n_in,
                              void* d_out, int out_size, void* d_ws, size_t ws_size,
                              hipStream_t stream) {
  const float* in = (const float*)d_in[0];
  float* out = (float*)d_out;
  const size_t pn_bytes = (size_t)NROWS * DIM * sizeof(ushort);

  if (ws_size >= pn_bytes + 2 * sizeof(float)) {
    ushort* pn   = (ushort*)d_ws;
    float* accum = (float*)((char*)d_ws + pn_bytes);
    prep_kernel<0><<<NROWS, 256, 0, stream>>>(in, pn, nullptr, accum);
    tri_gemm<<<NBLK, 256, 0, stream>>>(pn, accum);
    finalize_kernel<<<1, 64, 0, stream>>>(accum, out);
  } else {
    float* invn  = (float*)d_ws;
    float* accum = (float*)((char*)d_ws + NROWS * sizeof(float));
    prep_kernel<1><<<NROWS, 256, 0, stream>>>(in, nullptr, invn, accum);
    tri_gemm_fly<<<NBLK, 256, 0, stream>>>(in, invn, accum);
    finalize_kernel<<<1, 64, 0, stream>>>(accum, out);
  }
}

// Round 4
// 67.697 us; speedup vs baseline: 1.3264x; 1.3264x over previous
//
#include <hip/hip_runtime.h>
#include <stdint.h>

#define MARGIN 0.3f
#define NROWS 4096
#define DIM   2048
#define BT    128
#define BK    64
#define NB    (NROWS / BT)          // 32
#define NBLK  (NB * (NB + 1) / 2)   // 528

typedef float f32x4 __attribute__((ext_vector_type(4)));
typedef short s16x8 __attribute__((ext_vector_type(8)));

__device__ __forceinline__ ushort f32_to_bf16(float f) {
  uint32_t u = __float_as_uint(f);
  return (ushort)((u + 0x7FFFu + ((u >> 16) & 1u)) >> 16);  // RNE, no NaN in data
}

// async global->LDS, 16B per lane. LDS dest is wave-uniform base + lane*16
// (linear). The k-slot XOR swizzle is carried on the GLOBAL source address.
__device__ __forceinline__ void async_load16(const ushort* g, ushort* l) {
  __builtin_amdgcn_global_load_lds(
      (const __attribute__((address_space(1))) uint32_t*)g,
      (__attribute__((address_space(3))) uint32_t*)l, 16, 0, 0);
}

// ---------------------------------------------------------------------------
// prep: row L2-norm. FLY=0: write normalized bf16 matrix. FLY=1: write 1/norm.
// Also zeroes the accumulators (block 0, thread 0).
// ---------------------------------------------------------------------------
template <int FLY>
__global__ __launch_bounds__(256) void prep_kernel(const float* __restrict__ in,
                                                   ushort* __restrict__ pn,
                                                   float* __restrict__ invn,
                                                   float* __restrict__ accum) {
  const int row = blockIdx.x;
  const int tid = threadIdx.x;
  if (row == 0 && tid == 0) { accum[0] = 0.f; accum[1] = 0.f; }

  const float4* rp = (const float4*)(in + (size_t)row * DIM);
  float4 v0 = rp[tid * 2];
  float4 v1 = rp[tid * 2 + 1];
  float ss = v0.x*v0.x + v0.y*v0.y + v0.z*v0.z + v0.w*v0.w
           + v1.x*v1.x + v1.y*v1.y + v1.z*v1.z + v1.w*v1.w;
  #pragma unroll
  for (int off = 32; off; off >>= 1) ss += __shfl_down(ss, off);

  __shared__ float wred[4];
  __shared__ float stot;
  const int lane = tid & 63, w = tid >> 6;
  if (lane == 0) wred[w] = ss;
  __syncthreads();
  if (tid == 0) stot = wred[0] + wred[1] + wred[2] + wred[3];
  __syncthreads();
  const float inv = 1.0f / fmaxf(sqrtf(stot), 1e-12f);

  if (FLY) {
    if (tid == 0) invn[row] = inv;
  } else {
    int4 pack;
    ushort* h = (ushort*)&pack;
    h[0] = f32_to_bf16(v0.x * inv); h[1] = f32_to_bf16(v0.y * inv);
    h[2] = f32_to_bf16(v0.z * inv); h[3] = f32_to_bf16(v0.w * inv);
    h[4] = f32_to_bf16(v1.x * inv); h[5] = f32_to_bf16(v1.y * inv);
    h[6] = f32_to_bf16(v1.z * inv); h[7] = f32_to_bf16(v1.w * inv);
    *(int4*)(pn + (size_t)row * DIM + tid * 8) = pack;
  }
}

// ---------------------------------------------------------------------------
// tri_gemm: one block per upper-triangular 128x128 super-tile of sim = Pn Pn^T.
// 512 threads = 8 waves (2 x 4): each wave a 64x32 sub-tile as 4x2 fragments
// of 16x16x32 MFMA over BK=64 K-steps. Single-buffer LDS, 2-barrier loop
// (round-2 structure, which the compiler schedules well); the extra waves
// (~4.1 waves/SIMD at 2.06 blocks/CU) provide the latency hiding the 2-phase
// structure needs. Staging via global_load_lds (16B/lane, linear LDS dest)
// with the k-slot XOR swizzle on the GLOBAL source address; fragment
// ds_read_b128 applies the same XOR -> conflict-free (verified 0 in R2).
// ---------------------------------------------------------------------------
__global__ __launch_bounds__(512) void tri_gemm(const ushort* __restrict__ pn,
                                                float* __restrict__ accum) {
  int t = blockIdx.x, bi = 0;
  while (t >= NB - bi) { t -= NB - bi; ++bi; }
  const int bj = bi + t;

  __shared__ __align__(16) ushort Asm[BT * BK];   // 16 KB, rows of 128 B
  __shared__ __align__(16) ushort Bsm[BT * BK];   // 16 KB

  const int tid  = threadIdx.x;
  const int lane = tid & 63;
  const int w    = tid >> 6;          // 0..7
  const int wr   = w >> 2;            // 0..1  (64-row band)
  const int wc   = w & 3;             // 0..3  (32-col band)

  f32x4 acc[4][2] = {};
  const int rowA = bi * BT, rowB = bj * BT;

  // staging: 1 KB chunk = 8 rows x 128 B; lane l -> row +(l>>3), stored slot
  // (l&7); global true-k slot = (l&7) ^ (l>>3)  [row&7 == l>>3]
  const int srow  = (lane >> 3);
  const int gslot = (lane & 7) ^ srow;

  for (int k0 = 0; k0 < DIM; k0 += BK) {
    if (k0) __syncthreads();  // prior reads done before LDS overwrite
    #pragma unroll
    for (int q = 0; q < 2; ++q) {
      const int r = w * 16 + q * 8;   // chunk base row (multiple of 8)
      async_load16(pn + (size_t)(rowA + r + srow) * DIM + k0 + gslot * 8, Asm + r * BK);
      async_load16(pn + (size_t)(rowB + r + srow) * DIM + k0 + gslot * 8, Bsm + r * BK);
    }
    __syncthreads();  // drains vmcnt(0): global_load_lds data visible

    s16x8 af[2][4], bfv[2][2];
    const int fr = lane & 15, hi = lane >> 4;
    #pragma unroll
    for (int kk = 0; kk < 2; ++kk) {
      #pragma unroll
      for (int m = 0; m < 4; ++m) {
        const int ra = wr * 64 + m * 16 + fr;
        af[kk][m] = *(const s16x8*)(Asm + ra * BK + ((kk * 4 + hi) ^ (ra & 7)) * 8);
      }
      #pragma unroll
      for (int n = 0; n < 2; ++n) {
        const int rb = wc * 32 + n * 16 + fr;
        bfv[kk][n] = *(const s16x8*)(Bsm + rb * BK + ((kk * 4 + hi) ^ (rb & 7)) * 8);
      }
    }
    #pragma unroll
    for (int kk = 0; kk < 2; ++kk)
      #pragma unroll
      for (int m = 0; m < 4; ++m)
        #pragma unroll
        for (int n = 0; n < 2; ++n)
          acc[m][n] = __builtin_amdgcn_mfma_f32_16x16x32_bf16(af[kk][m], bfv[kk][n],
                                                              acc[m][n], 0, 0, 0);
  }

  // ---- epilogue: mask + reduce ----
  float lsum = 0.f, lcnt = 0.f;
  const int gib = rowA + wr * 64;
  const int gjb = rowB + wc * 32;
  #pragma unroll
  for (int m = 0; m < 4; ++m) {
    #pragma unroll
    for (int n = 0; n < 2; ++n) {
      #pragma unroll
      for (int r = 0; r < 4; ++r) {
        int gi = gib + m * 16 + (lane >> 4) * 4 + r;
        int gj = gjb + n * 16 + (lane & 15);
        float s = acc[m][n][r];
        if (gi < gj && s > MARGIN) { lsum += s - MARGIN; lcnt += 1.f; }
      }
    }
  }
  #pragma unroll
  for (int off = 32; off; off >>= 1) {
    lsum += __shfl_down(lsum, off);
    lcnt += __shfl_down(lcnt, off);
  }
  __shared__ float rs[8], rc[8];
  if (lane == 0) { rs[w] = lsum; rc[w] = lcnt; }
  __syncthreads();
  if (tid == 0) {
    float s = 0.f, c = 0.f;
    #pragma unroll
    for (int i = 0; i < 8; ++i) { s += rs[i]; c += rc[i]; }
    atomicAdd(&accum[0], s);
    atomicAdd(&accum[1], c);
  }
}

// ---------------------------------------------------------------------------
// Fallback (tiny workspace): round-2 single-buffer structure, on-the-fly
// convert, 256 threads / 4 waves, each wave 64x64 (acc 4x4).
// ---------------------------------------------------------------------------
__global__ __launch_bounds__(256) void tri_gemm_fly(const float* __restrict__ inF,
                                                    const float* __restrict__ invn,
                                                    float* __restrict__ accum) {
  int t = blockIdx.x, bi = 0;
  while (t >= NB - bi) { t -= NB - bi; ++bi; }
  const int bj = bi + t;

  __shared__ __align__(16) ushort Asm[BT * BK];
  __shared__ __align__(16) ushort Bsm[BT * BK];

  const int tid  = threadIdx.x;
  const int lane = tid & 63;
  const int w    = tid >> 6;
  const int wr   = w >> 1, wc = w & 1;

  f32x4 acc[4][4] = {};
  const int rowA = bi * BT, rowB = bj * BT;

  for (int k0 = 0; k0 < DIM; k0 += BK) {
    if (k0) __syncthreads();
    #pragma unroll
    for (int p = 0; p < 8; ++p) {
      int c   = p * 256 + tid;
      int isB = c >> 10;
      int cc  = c & 1023;
      int r   = cc >> 3;
      int s   = cc & 7;
      const int grow = (isB ? rowB : rowA) + r;
      const float4* src = (const float4*)(inF + (size_t)grow * DIM + k0 + s * 8);
      float4 v0 = src[0], v1 = src[1];
      int4 pack;
      ushort* h = (ushort*)&pack;
      h[0] = f32_to_bf16(v0.x); h[1] = f32_to_bf16(v0.y);
      h[2] = f32_to_bf16(v0.z); h[3] = f32_to_bf16(v0.w);
      h[4] = f32_to_bf16(v1.x); h[5] = f32_to_bf16(v1.y);
      h[6] = f32_to_bf16(v1.z); h[7] = f32_to_bf16(v1.w);
      *(int4*)((isB ? Bsm : Asm) + r * BK + (s ^ (r & 7)) * 8) = pack;
    }
    __syncthreads();

    s16x8 af[2][4], bfv[2][4];
    const int fr = lane & 15, hi = lane >> 4;
    #pragma unroll
    for (int kk = 0; kk < 2; ++kk)
      #pragma unroll
      for (int m = 0; m < 4; ++m) {
        const int ra = wr * 64 + m * 16 + fr;
        af[kk][m] = *(const s16x8*)(Asm + ra * BK + ((kk * 4 + hi) ^ (ra & 7)) * 8);
        const int rb = wc * 64 + m * 16 + fr;
        bfv[kk][m] = *(const s16x8*)(Bsm + rb * BK + ((kk * 4 + hi) ^ (rb & 7)) * 8);
      }
    #pragma unroll
    for (int kk = 0; kk < 2; ++kk)
      #pragma unroll
      for (int m = 0; m < 4; ++m)
        #pragma unroll
        for (int n = 0; n < 4; ++n)
          acc[m][n] = __builtin_amdgcn_mfma_f32_16x16x32_bf16(af[kk][m], bfv[kk][n],
                                                              acc[m][n], 0, 0, 0);
  }

  float lsum = 0.f, lcnt = 0.f;
  const int gib = rowA + wr * 64;
  const int gjb = rowB + wc * 64;
  #pragma unroll
  for (int m = 0; m < 4; ++m)
    #pragma unroll
    for (int n = 0; n < 4; ++n)
      #pragma unroll
      for (int r = 0; r < 4; ++r) {
        int gi = gib + m * 16 + (lane >> 4) * 4 + r;
        int gj = gjb + n * 16 + (lane & 15);
        float s = acc[m][n][r] * invn[gi] * invn[gj];
        if (gi < gj && s > MARGIN) { lsum += s - MARGIN; lcnt += 1.f; }
      }
  #pragma unroll
  for (int off = 32; off; off >>= 1) {
    lsum += __shfl_down(lsum, off);
    lcnt += __shfl_down(lcnt, off);
  }
  __shared__ float rs[4], rc[4];
  if (lane == 0) { rs[w] = lsum; rc[w] = lcnt; }
  __syncthreads();
  if (tid == 0) {
    atomicAdd(&accum[0], rs[0] + rs[1] + rs[2] + rs[3]);
    atomicAdd(&accum[1], rc[0] + rc[1] + rc[2] + rc[3]);
  }
}

__global__ void finalize_kernel(const float* __restrict__ accum, float* __restrict__ out) {
  if (threadIdx.x == 0) out[0] = (accum[1] < 0.5f) ? 0.0f : accum[0] / accum[1];
}

extern "C" void kernel_launch(void* const* d_in, const int* in_sizes, int n_in,
                              void* d_out, int out_size, void* d_ws, size_t ws_size,
                              hipStream_t stream) {
  const float* in = (const float*)d_in[0];
  float* out = (float*)d_out;
  const size_t pn_bytes = (size_t)NROWS * DIM * sizeof(ushort);

  if (ws_size >= pn_bytes + 2 * sizeof(float)) {
    ushort* pn   = (ushort*)d_ws;
    float* accum = (float*)((char*)d_ws + pn_bytes);
    prep_kernel<0><<<NROWS, 256, 0, stream>>>(in, pn, nullptr, accum);
    tri_gemm<<<NBLK, 512, 0, stream>>>(pn, accum);
    finalize_kernel<<<1, 64, 0, stream>>>(accum, out);
  } else {
    float* invn  = (float*)d_ws;
    float* accum = (float*)((char*)d_ws + NROWS * sizeof(float));
    prep_kernel<1><<<NROWS, 256, 0, stream>>>(in, nullptr, invn, accum);
    tri_gemm_fly<<<NBLK, 256, 0, stream>>>(in, invn, accum);
    finalize_kernel<<<1, 64, 0, stream>>>(accum, out);
  }
}

// Round 5
// 59.507 us; speedup vs baseline: 1.5090x; 1.1376x over previous
//
#include <hip/hip_runtime.h>
#include <hip/hip_fp8.h>
#include <stdint.h>

#define MARGIN 0.3f
#define NROWS 4096
#define DIM   2048
#define BT    128
#define BK    128                   // fp8 K-elements (= bytes) per tile row
#define NB    (NROWS / BT)          // 32
#define NBLK  (NB * (NB + 1) / 2)   // 528

typedef float f32x4 __attribute__((ext_vector_type(4)));
typedef int   i32x8 __attribute__((ext_vector_type(8)));
typedef short s16x8 __attribute__((ext_vector_type(8)));

__device__ __forceinline__ unsigned char f32_to_fp8(float f) {
  __hip_fp8_e4m3 h(f);                 // OCP e4m3fn on gfx950
  return (unsigned char)h.__x;
}

__device__ __forceinline__ ushort f32_to_bf16(float f) {
  uint32_t u = __float_as_uint(f);
  return (ushort)((u + 0x7FFFu + ((u >> 16) & 1u)) >> 16);
}

// async global->LDS, 16B per lane. LDS dest is wave-uniform base + lane*16
// (linear). The k-slot XOR swizzle is carried on the GLOBAL source address.
__device__ __forceinline__ void async_load16(const void* g, void* l) {
  __builtin_amdgcn_global_load_lds(
      (const __attribute__((address_space(1))) uint32_t*)g,
      (__attribute__((address_space(3))) uint32_t*)l, 16, 0, 0);
}

// ---------------------------------------------------------------------------
// prep: row L2-norm. FLY=0: write normalized fp8(e4m3) matrix. FLY=1: 1/norm.
// Also zeroes the accumulators.
// ---------------------------------------------------------------------------
template <int FLY>
__global__ __launch_bounds__(256) void prep_kernel(const float* __restrict__ in,
                                                   unsigned char* __restrict__ pn,
                                                   float* __restrict__ invn,
                                                   float* __restrict__ accum) {
  const int row = blockIdx.x;
  const int tid = threadIdx.x;
  if (row == 0 && tid == 0) { accum[0] = 0.f; accum[1] = 0.f; }

  const float4* rp = (const float4*)(in + (size_t)row * DIM);
  float4 v0 = rp[tid * 2];
  float4 v1 = rp[tid * 2 + 1];
  float ss = v0.x*v0.x + v0.y*v0.y + v0.z*v0.z + v0.w*v0.w
           + v1.x*v1.x + v1.y*v1.y + v1.z*v1.z + v1.w*v1.w;
  #pragma unroll
  for (int off = 32; off; off >>= 1) ss += __shfl_down(ss, off);

  __shared__ float wred[4];
  __shared__ float stot;
  const int lane = tid & 63, w = tid >> 6;
  if (lane == 0) wred[w] = ss;
  __syncthreads();
  if (tid == 0) stot = wred[0] + wred[1] + wred[2] + wred[3];
  __syncthreads();
  const float inv = 1.0f / fmaxf(sqrtf(stot), 1e-12f);

  if (FLY) {
    if (tid == 0) invn[row] = inv;
  } else {
    union { unsigned char b[8]; uint2 u; } pack;
    pack.b[0] = f32_to_fp8(v0.x * inv); pack.b[1] = f32_to_fp8(v0.y * inv);
    pack.b[2] = f32_to_fp8(v0.z * inv); pack.b[3] = f32_to_fp8(v0.w * inv);
    pack.b[4] = f32_to_fp8(v1.x * inv); pack.b[5] = f32_to_fp8(v1.y * inv);
    pack.b[6] = f32_to_fp8(v1.z * inv); pack.b[7] = f32_to_fp8(v1.w * inv);
    *(uint2*)(pn + (size_t)row * DIM + tid * 8) = pack.u;
  }
}

// ---------------------------------------------------------------------------
// tri_gemm: one block per upper-triangular 128x128 super-tile of sim = Pn Pn^T.
// fp8 e4m3 inputs via mfma_scale_f32_16x16x128_f8f6f4 with all scales = 1.0
// (e8m0 byte 0x7F), i.e. a plain fp8 GEMM with K=128 per MFMA instruction.
// 512 threads = 8 waves (2x4), wave tile 64x32 (4x2 frags). BK=128 fp8 bytes:
// same 32 KB LDS, half the K-steps (16) of the bf16 version. Staging via
// global_load_lds 16B/lane with k-slot XOR swizzle on the GLOBAL source addr
// (row = 8 slots of 16B, identical geometry to the verified bf16 layout);
// fragment ds_read_b128 pairs apply the same XOR -> conflict-free.
// ---------------------------------------------------------------------------
__global__ __launch_bounds__(512) void tri_gemm(const unsigned char* __restrict__ pn,
                                                float* __restrict__ accum) {
  int t = blockIdx.x, bi = 0;
  while (t >= NB - bi) { t -= NB - bi; ++bi; }
  const int bj = bi + t;

  __shared__ __align__(16) unsigned char Asm[BT * BK];   // 16 KB
  __shared__ __align__(16) unsigned char Bsm[BT * BK];   // 16 KB

  const int tid  = threadIdx.x;
  const int lane = tid & 63;
  const int w    = tid >> 6;          // 0..7
  const int wr   = w >> 2;            // 0..1  (64-row band)
  const int wc   = w & 3;             // 0..3  (32-col band)

  f32x4 acc[4][2] = {};
  const int rowA = bi * BT, rowB = bj * BT;

  // staging: 1 KB chunk = 8 rows x 128 B; lane l -> row +(l>>3), stored slot
  // (l&7); global true-k slot = (l&7) ^ (l>>3)
  const int srow  = (lane >> 3);
  const int gslot = (lane & 7) ^ srow;

  for (int k0 = 0; k0 < DIM; k0 += BK) {
    if (k0) __syncthreads();  // prior reads done before LDS overwrite
    #pragma unroll
    for (int q = 0; q < 2; ++q) {
      const int r = w * 16 + q * 8;   // chunk base row (multiple of 8)
      async_load16(pn + (size_t)(rowA + r + srow) * DIM + k0 + gslot * 16, Asm + r * BK);
      async_load16(pn + (size_t)(rowB + r + srow) * DIM + k0 + gslot * 16, Bsm + r * BK);
    }
    __syncthreads();  // drains vmcnt(0): global_load_lds data visible

    // fragments: lane l -> row (l&15), k-group g=(l>>4) covering bytes
    // [g*32, g*32+32) = stored 16B slots (2g)^(row&7), (2g+1)^(row&7)
    i32x8 af[4], bfv[2];
    const int fr = lane & 15, g = lane >> 4;
    #pragma unroll
    for (int m = 0; m < 4; ++m) {
      const int ra = wr * 64 + m * 16 + fr;
      const unsigned char* base = Asm + ra * BK;
      int4 lo = *(const int4*)(base + ((2 * g)     ^ (ra & 7)) * 16);
      int4 hi = *(const int4*)(base + ((2 * g + 1) ^ (ra & 7)) * 16);
      i32x8 v = {lo.x, lo.y, lo.z, lo.w, hi.x, hi.y, hi.z, hi.w};
      af[m] = v;
    }
    #pragma unroll
    for (int n = 0; n < 2; ++n) {
      const int rb = wc * 32 + n * 16 + fr;
      const unsigned char* base = Bsm + rb * BK;
      int4 lo = *(const int4*)(base + ((2 * g)     ^ (rb & 7)) * 16);
      int4 hi = *(const int4*)(base + ((2 * g + 1) ^ (rb & 7)) * 16);
      i32x8 v = {lo.x, lo.y, lo.z, lo.w, hi.x, hi.y, hi.z, hi.w};
      bfv[n] = v;
    }

    #pragma unroll
    for (int m = 0; m < 4; ++m)
      #pragma unroll
      for (int n = 0; n < 2; ++n)
        acc[m][n] = __builtin_amdgcn_mfma_scale_f32_16x16x128_f8f6f4(
            af[m], bfv[n], acc[m][n],
            0, 0,                      // cbsz=fp8(e4m3), blgp=fp8(e4m3)
            0, 0x7F7F7F7F,             // scale_a: all e8m0 bytes = 1.0
            0, 0x7F7F7F7F);            // scale_b: all e8m0 bytes = 1.0
  }

  // ---- epilogue: mask + reduce (C/D layout is shape-determined) ----
  float lsum = 0.f, lcnt = 0.f;
  const int gib = rowA + wr * 64;
  const int gjb = rowB + wc * 32;
  #pragma unroll
  for (int m = 0; m < 4; ++m) {
    #pragma unroll
    for (int n = 0; n < 2; ++n) {
      #pragma unroll
      for (int r = 0; r < 4; ++r) {
        int gi = gib + m * 16 + (lane >> 4) * 4 + r;
        int gj = gjb + n * 16 + (lane & 15);
        float s = acc[m][n][r];
        if (gi < gj && s > MARGIN) { lsum += s - MARGIN; lcnt += 1.f; }
      }
    }
  }
  #pragma unroll
  for (int off = 32; off; off >>= 1) {
    lsum += __shfl_down(lsum, off);
    lcnt += __shfl_down(lcnt, off);
  }
  __shared__ float rs[8], rc[8];
  if (lane == 0) { rs[w] = lsum; rc[w] = lcnt; }
  __syncthreads();
  if (tid == 0) {
    float s = 0.f, c = 0.f;
    #pragma unroll
    for (int i = 0; i < 8; ++i) { s += rs[i]; c += rc[i]; }
    atomicAdd(&accum[0], s);
    atomicAdd(&accum[1], c);
  }
}

// ---------------------------------------------------------------------------
// Fallback (tiny workspace): bf16 on-the-fly convert, 256 threads / 4 waves,
// single-buffer, BK=64 bf16 (verified R2 structure).
// ---------------------------------------------------------------------------
__global__ __launch_bounds__(256) void tri_gemm_fly(const float* __restrict__ inF,
                                                    const float* __restrict__ invn,
                                                    float* __restrict__ accum) {
  enum { FBK = 64 };
  int t = blockIdx.x, bi = 0;
  while (t >= NB - bi) { t -= NB - bi; ++bi; }
  const int bj = bi + t;

  __shared__ __align__(16) ushort Asm[BT * FBK];
  __shared__ __align__(16) ushort Bsm[BT * FBK];

  const int tid  = threadIdx.x;
  const int lane = tid & 63;
  const int w    = tid >> 6;
  const int wr   = w >> 1, wc = w & 1;

  f32x4 acc[4][4] = {};
  const int rowA = bi * BT, rowB = bj * BT;

  for (int k0 = 0; k0 < DIM; k0 += FBK) {
    if (k0) __syncthreads();
    #pragma unroll
    for (int p = 0; p < 8; ++p) {
      int c   = p * 256 + tid;
      int isB = c >> 10;
      int cc  = c & 1023;
      int r   = cc >> 3;
      int s   = cc & 7;
      const int grow = (isB ? rowB : rowA) + r;
      const float4* src = (const float4*)(inF + (size_t)grow * DIM + k0 + s * 8);
      float4 v0 = src[0], v1 = src[1];
      int4 pack;
      ushort* h = (ushort*)&pack;
      h[0] = f32_to_bf16(v0.x); h[1] = f32_to_bf16(v0.y);
      h[2] = f32_to_bf16(v0.z); h[3] = f32_to_bf16(v0.w);
      h[4] = f32_to_bf16(v1.x); h[5] = f32_to_bf16(v1.y);
      h[6] = f32_to_bf16(v1.z); h[7] = f32_to_bf16(v1.w);
      *(int4*)((isB ? Bsm : Asm) + r * FBK + (s ^ (r & 7)) * 8) = pack;
    }
    __syncthreads();

    s16x8 af[2][4], bfv[2][4];
    const int fr = lane & 15, hi = lane >> 4;
    #pragma unroll
    for (int kk = 0; kk < 2; ++kk)
      #pragma unroll
      for (int m = 0; m < 4; ++m) {
        const int ra = wr * 64 + m * 16 + fr;
        af[kk][m] = *(const s16x8*)(Asm + ra * FBK + ((kk * 4 + hi) ^ (ra & 7)) * 8);
        const int rb = wc * 64 + m * 16 + fr;
        bfv[kk][m] = *(const s16x8*)(Bsm + rb * FBK + ((kk * 4 + hi) ^ (rb & 7)) * 8);
      }
    #pragma unroll
    for (int kk = 0; kk < 2; ++kk)
      #pragma unroll
      for (int m = 0; m < 4; ++m)
        #pragma unroll
        for (int n = 0; n < 4; ++n)
          acc[m][n] = __builtin_amdgcn_mfma_f32_16x16x32_bf16(af[kk][m], bfv[kk][n],
                                                              acc[m][n], 0, 0, 0);
  }

  float lsum = 0.f, lcnt = 0.f;
  const int gib = rowA + wr * 64;
  const int gjb = rowB + wc * 64;
  #pragma unroll
  for (int m = 0; m < 4; ++m)
    #pragma unroll
    for (int n = 0; n < 4; ++n)
      #pragma unroll
      for (int r = 0; r < 4; ++r) {
        int gi = gib + m * 16 + (lane >> 4) * 4 + r;
        int gj = gjb + n * 16 + (lane & 15);
        float s = acc[m][n][r] * invn[gi] * invn[gj];
        if (gi < gj && s > MARGIN) { lsum += s - MARGIN; lcnt += 1.f; }
      }
  #pragma unroll
  for (int off = 32; off; off >>= 1) {
    lsum += __shfl_down(lsum, off);
    lcnt += __shfl_down(lcnt, off);
  }
  __shared__ float rs[4], rc[4];
  if (lane == 0) { rs[w] = lsum; rc[w] = lcnt; }
  __syncthreads();
  if (tid == 0) {
    atomicAdd(&accum[0], rs[0] + rs[1] + rs[2] + rs[3]);
    atomicAdd(&accum[1], rc[0] + rc[1] + rc[2] + rc[3]);
  }
}

__global__ void finalize_kernel(const float* __restrict__ accum, float* __restrict__ out) {
  if (threadIdx.x == 0) out[0] = (accum[1] < 0.5f) ? 0.0f : accum[0] / accum[1];
}

extern "C" void kernel_launch(void* const* d_in, const int* in_sizes, int n_in,
                              void* d_out, int out_size, void* d_ws, size_t ws_size,
                              hipStream_t stream) {
  const float* in = (const float*)d_in[0];
  float* out = (float*)d_out;
  const size_t pn_bytes = (size_t)NROWS * DIM;   // fp8: 8.4 MB

  if (ws_size >= pn_bytes + 2 * sizeof(float)) {
    unsigned char* pn = (unsigned char*)d_ws;
    float* accum = (float*)((char*)d_ws + pn_bytes);
    prep_kernel<0><<<NROWS, 256, 0, stream>>>(in, pn, nullptr, accum);
    tri_gemm<<<NBLK, 512, 0, stream>>>(pn, accum);
    finalize_kernel<<<1, 64, 0, stream>>>(accum, out);
  } else {
    float* invn  = (float*)d_ws;
    float* accum = (float*)((char*)d_ws + NROWS * sizeof(float));
    prep_kernel<1><<<NROWS, 256, 0, stream>>>(in, nullptr, invn, accum);
    tri_gemm_fly<<<NBLK, 256, 0, stream>>>(in, invn, accum);
    finalize_kernel<<<1, 64, 0, stream>>>(accum, out);
  }
}

// Round 6
// 46.689 us; speedup vs baseline: 1.9232x; 1.2745x over previous
//
#include <hip/hip_runtime.h>
#include <hip/hip_fp8.h>
#include <stdint.h>

#define MARGIN 0.3f
#define NROWS 4096
#define DIM   2048
#define BT    128
#define BK    128                   // fp8 K-elements (= bytes) per tile row
#define NB    (NROWS / BT)          // 32
#define NBLK  (NB * (NB + 1) / 2)   // 528 (divisible by 8 -> clean XCD swizzle)

typedef float f32x4 __attribute__((ext_vector_type(4)));
typedef int   i32x4 __attribute__((ext_vector_type(4)));
typedef int   i32x8 __attribute__((ext_vector_type(8)));
typedef short s16x8 __attribute__((ext_vector_type(8)));

__device__ __forceinline__ unsigned char f32_to_fp8(float f) {
  __hip_fp8_e4m3 h(f);                 // OCP e4m3fn on gfx950
  return (unsigned char)h.__x;
}

__device__ __forceinline__ ushort f32_to_bf16(float f) {
  uint32_t u = __float_as_uint(f);
  return (ushort)((u + 0x7FFFu + ((u >> 16) & 1u)) >> 16);
}

// async global->LDS, 16B per lane. LDS dest is wave-uniform base + lane*16
// (linear). The k-slot XOR swizzle is carried on the GLOBAL source address.
__device__ __forceinline__ void async_load16(const void* g, void* l) {
  __builtin_amdgcn_global_load_lds(
      (const __attribute__((address_space(1))) uint32_t*)g,
      (__attribute__((address_space(3))) uint32_t*)l, 16, 0, 0);
}

// ---------------------------------------------------------------------------
// prep: row L2-norm. FLY=0: write normalized fp8(e4m3) matrix. FLY=1: 1/norm.
// Also zeroes the accumulators.
// ---------------------------------------------------------------------------
template <int FLY>
__global__ __launch_bounds__(256) void prep_kernel(const float* __restrict__ in,
                                                   unsigned char* __restrict__ pn,
                                                   float* __restrict__ invn,
                                                   float* __restrict__ accum) {
  const int row = blockIdx.x;
  const int tid = threadIdx.x;
  if (row == 0 && tid == 0) { accum[0] = 0.f; accum[1] = 0.f; }

  const float4* rp = (const float4*)(in + (size_t)row * DIM);
  float4 v0 = rp[tid * 2];
  float4 v1 = rp[tid * 2 + 1];
  float ss = v0.x*v0.x + v0.y*v0.y + v0.z*v0.z + v0.w*v0.w
           + v1.x*v1.x + v1.y*v1.y + v1.z*v1.z + v1.w*v1.w;
  #pragma unroll
  for (int off = 32; off; off >>= 1) ss += __shfl_down(ss, off);

  __shared__ float wred[4];
  __shared__ float stot;
  const int lane = tid & 63, w = tid >> 6;
  if (lane == 0) wred[w] = ss;
  __syncthreads();
  if (tid == 0) stot = wred[0] + wred[1] + wred[2] + wred[3];
  __syncthreads();
  const float inv = 1.0f / fmaxf(sqrtf(stot), 1e-12f);

  if (FLY) {
    if (tid == 0) invn[row] = inv;
  } else {
    union { unsigned char b[8]; uint2 u; } pack;
    pack.b[0] = f32_to_fp8(v0.x * inv); pack.b[1] = f32_to_fp8(v0.y * inv);
    pack.b[2] = f32_to_fp8(v0.z * inv); pack.b[3] = f32_to_fp8(v0.w * inv);
    pack.b[4] = f32_to_fp8(v1.x * inv); pack.b[5] = f32_to_fp8(v1.y * inv);
    pack.b[6] = f32_to_fp8(v1.z * inv); pack.b[7] = f32_to_fp8(v1.w * inv);
    *(uint2*)(pn + (size_t)row * DIM + tid * 8) = pack.u;
  }
}

// ---------------------------------------------------------------------------
// tri_gemm: one block per upper-triangular 128x128 super-tile of sim = Pn Pn^T.
// fp8 e4m3 via mfma_scale_f32_16x16x128_f8f6f4 with all scales = 1.0 (0x7F),
// i.e. a plain fp8 GEMM with K=128 per MFMA. 256 threads = 4 waves (2x2),
// wave tile 64x64 (4x4 frags) -- minimizes per-output LDS-read traffic
// (BK*(1/64+1/64) = 4B/out, 33% less than 8-wave 64x32). BK=128: 16 K-steps.
// Fragments: two explicit i32x4 ds_read_b128 + shufflevector (keeps the
// conflict-free b128 pattern; R5's aggregate-init split them -> 3.2M confl).
// Staging via global_load_lds 16B/lane, k-slot XOR swizzle on the GLOBAL
// source address (linear LDS dest).
// ---------------------------------------------------------------------------
__global__ __launch_bounds__(256) void tri_gemm(const unsigned char* __restrict__ pn,
                                                float* __restrict__ accum) {
  // XCD-aware bijective swizzle (NBLK % 8 == 0): consecutive tiles (sharing
  // the A-panel) land on the same XCD's L2.
  const int b = blockIdx.x;
  int t = (b & 7) * (NBLK / 8) + (b >> 3);
  int bi = 0;
  while (t >= NB - bi) { t -= NB - bi; ++bi; }
  const int bj = bi + t;

  __shared__ __align__(16) unsigned char Asm[BT * BK];   // 16 KB
  __shared__ __align__(16) unsigned char Bsm[BT * BK];   // 16 KB

  const int tid  = threadIdx.x;
  const int lane = tid & 63;
  const int w    = tid >> 6;          // 0..3
  const int wr   = w >> 1;            // 0..1  (64-row band of A)
  const int wc   = w & 1;             // 0..1  (64-row band of B)

  f32x4 acc[4][4] = {};
  const int rowA = bi * BT, rowB = bj * BT;

  // staging: 1 KB chunk = 8 rows x 128 B; lane l -> row +(l>>3), stored slot
  // (l&7); global true-k slot = (l&7) ^ (l>>3)
  const int srow  = (lane >> 3);
  const int gslot = (lane & 7) ^ srow;

  for (int k0 = 0; k0 < DIM; k0 += BK) {
    if (k0) __syncthreads();  // prior reads done before LDS overwrite
    #pragma unroll
    for (int q = 0; q < 4; ++q) {
      const int r = w * 32 + q * 8;   // chunk base row (multiple of 8)
      async_load16(pn + (size_t)(rowA + r + srow) * DIM + k0 + gslot * 16, Asm + r * BK);
      async_load16(pn + (size_t)(rowB + r + srow) * DIM + k0 + gslot * 16, Bsm + r * BK);
    }
    __syncthreads();  // drains vmcnt(0): global_load_lds data visible

    // fragments: lane l -> row (l&15), k-group g=(l>>4) covering bytes
    // [g*32, g*32+32) = stored 16B slots (2g)^(row&7), (2g+1)^(row&7)
    const int fr = lane & 15, g = lane >> 4;
    i32x8 af[4], bfv[4];
    #pragma unroll
    for (int m = 0; m < 4; ++m) {
      const int ra = wr * 64 + m * 16 + fr;
      const unsigned char* base = Asm + ra * BK;
      i32x4 lo = *(const i32x4*)(base + ((2 * g)     ^ (ra & 7)) * 16);
      i32x4 hi = *(const i32x4*)(base + ((2 * g + 1) ^ (ra & 7)) * 16);
      af[m] = __builtin_shufflevector(lo, hi, 0, 1, 2, 3, 4, 5, 6, 7);
    }
    #pragma unroll
    for (int n = 0; n < 4; ++n) {
      const int rb = wc * 64 + n * 16 + fr;
      const unsigned char* base = Bsm + rb * BK;
      i32x4 lo = *(const i32x4*)(base + ((2 * g)     ^ (rb & 7)) * 16);
      i32x4 hi = *(const i32x4*)(base + ((2 * g + 1) ^ (rb & 7)) * 16);
      bfv[n] = __builtin_shufflevector(lo, hi, 0, 1, 2, 3, 4, 5, 6, 7);
    }

    #pragma unroll
    for (int m = 0; m < 4; ++m)
      #pragma unroll
      for (int n = 0; n < 4; ++n)
        acc[m][n] = __builtin_amdgcn_mfma_scale_f32_16x16x128_f8f6f4(
            af[m], bfv[n], acc[m][n],
            0, 0,                      // cbsz=fp8(e4m3), blgp=fp8(e4m3)
            0, 0x7F7F7F7F,             // scale_a: all e8m0 bytes = 1.0
            0, 0x7F7F7F7F);            // scale_b: all e8m0 bytes = 1.0
  }

  // ---- epilogue: mask + reduce (C/D layout is shape-determined) ----
  float lsum = 0.f, lcnt = 0.f;
  const int gib = rowA + wr * 64;
  const int gjb = rowB + wc * 64;
  #pragma unroll
  for (int m = 0; m < 4; ++m) {
    #pragma unroll
    for (int n = 0; n < 4; ++n) {
      #pragma unroll
      for (int r = 0; r < 4; ++r) {
        int gi = gib + m * 16 + (lane >> 4) * 4 + r;
        int gj = gjb + n * 16 + (lane & 15);
        float s = acc[m][n][r];
        if (gi < gj && s > MARGIN) { lsum += s - MARGIN; lcnt += 1.f; }
      }
    }
  }
  #pragma unroll
  for (int off = 32; off; off >>= 1) {
    lsum += __shfl_down(lsum, off);
    lcnt += __shfl_down(lcnt, off);
  }
  __shared__ float rs[4], rc[4];
  if (lane == 0) { rs[w] = lsum; rc[w] = lcnt; }
  __syncthreads();
  if (tid == 0) {
    atomicAdd(&accum[0], rs[0] + rs[1] + rs[2] + rs[3]);
    atomicAdd(&accum[1], rc[0] + rc[1] + rc[2] + rc[3]);
  }
}

// ---------------------------------------------------------------------------
// Fallback (tiny workspace): bf16 on-the-fly convert, 256 threads / 4 waves,
// single-buffer, BK=64 bf16 (verified R2 structure).
// ---------------------------------------------------------------------------
__global__ __launch_bounds__(256) void tri_gemm_fly(const float* __restrict__ inF,
                                                    const float* __restrict__ invn,
                                                    float* __restrict__ accum) {
  enum { FBK = 64 };
  int t = blockIdx.x, bi = 0;
  while (t >= NB - bi) { t -= NB - bi; ++bi; }
  const int bj = bi + t;

  __shared__ __align__(16) ushort Asm[BT * FBK];
  __shared__ __align__(16) ushort Bsm[BT * FBK];

  const int tid  = threadIdx.x;
  const int lane = tid & 63;
  const int w    = tid >> 6;
  const int wr   = w >> 1, wc = w & 1;

  f32x4 acc[4][4] = {};
  const int rowA = bi * BT, rowB = bj * BT;

  for (int k0 = 0; k0 < DIM; k0 += FBK) {
    if (k0) __syncthreads();
    #pragma unroll
    for (int p = 0; p < 8; ++p) {
      int c   = p * 256 + tid;
      int isB = c >> 10;
      int cc  = c & 1023;
      int r   = cc >> 3;
      int s   = cc & 7;
      const int grow = (isB ? rowB : rowA) + r;
      const float4* src = (const float4*)(inF + (size_t)grow * DIM + k0 + s * 8);
      float4 v0 = src[0], v1 = src[1];
      int4 pack;
      ushort* h = (ushort*)&pack;
      h[0] = f32_to_bf16(v0.x); h[1] = f32_to_bf16(v0.y);
      h[2] = f32_to_bf16(v0.z); h[3] = f32_to_bf16(v0.w);
      h[4] = f32_to_bf16(v1.x); h[5] = f32_to_bf16(v1.y);
      h[6] = f32_to_bf16(v1.z); h[7] = f32_to_bf16(v1.w);
      *(int4*)((isB ? Bsm : Asm) + r * FBK + (s ^ (r & 7)) * 8) = pack;
    }
    __syncthreads();

    s16x8 af[2][4], bfv[2][4];
    const int fr = lane & 15, hi = lane >> 4;
    #pragma unroll
    for (int kk = 0; kk < 2; ++kk)
      #pragma unroll
      for (int m = 0; m < 4; ++m) {
        const int ra = wr * 64 + m * 16 + fr;
        af[kk][m] = *(const s16x8*)(Asm + ra * FBK + ((kk * 4 + hi) ^ (ra & 7)) * 8);
        const int rb = wc * 64 + m * 16 + fr;
        bfv[kk][m] = *(const s16x8*)(Bsm + rb * FBK + ((kk * 4 + hi) ^ (rb & 7)) * 8);
      }
    #pragma unroll
    for (int kk = 0; kk < 2; ++kk)
      #pragma unroll
      for (int m = 0; m < 4; ++m)
        #pragma unroll
        for (int n = 0; n < 4; ++n)
          acc[m][n] = __builtin_amdgcn_mfma_f32_16x16x32_bf16(af[kk][m], bfv[kk][n],
                                                              acc[m][n], 0, 0, 0);
  }

  float lsum = 0.f, lcnt = 0.f;
  const int gib = rowA + wr * 64;
  const int gjb = rowB + wc * 64;
  #pragma unroll
  for (int m = 0; m < 4; ++m)
    #pragma unroll
    for (int n = 0; n < 4; ++n)
      #pragma unroll
      for (int r = 0; r < 4; ++r) {
        int gi = gib + m * 16 + (lane >> 4) * 4 + r;
        int gj = gjb + n * 16 + (lane & 15);
        float s = acc[m][n][r] * invn[gi] * invn[gj];
        if (gi < gj && s > MARGIN) { lsum += s - MARGIN; lcnt += 1.f; }
      }
  #pragma unroll
  for (int off = 32; off; off >>= 1) {
    lsum += __shfl_down(lsum, off);
    lcnt += __shfl_down(lcnt, off);
  }
  __shared__ float rs[4], rc[4];
  if (lane == 0) { rs[w] = lsum; rc[w] = lcnt; }
  __syncthreads();
  if (tid == 0) {
    atomicAdd(&accum[0], rs[0] + rs[1] + rs[2] + rs[3]);
    atomicAdd(&accum[1], rc[0] + rc[1] + rc[2] + rc[3]);
  }
}

__global__ void finalize_kernel(const float* __restrict__ accum, float* __restrict__ out) {
  if (threadIdx.x == 0) out[0] = (accum[1] < 0.5f) ? 0.0f : accum[0] / accum[1];
}

extern "C" void kernel_launch(void* const* d_in, const int* in_sizes, int n_in,
                              void* d_out, int out_size, void* d_ws, size_t ws_size,
                              hipStream_t stream) {
  const float* in = (const float*)d_in[0];
  float* out = (float*)d_out;
  const size_t pn_bytes = (size_t)NROWS * DIM;   // fp8: 8.4 MB

  if (ws_size >= pn_bytes + 2 * sizeof(float)) {
    unsigned char* pn = (unsigned char*)d_ws;
    float* accum = (float*)((char*)d_ws + pn_bytes);
    prep_kernel<0><<<NROWS, 256, 0, stream>>>(in, pn, nullptr, accum);
    tri_gemm<<<NBLK, 256, 0, stream>>>(pn, accum);
    finalize_kernel<<<1, 64, 0, stream>>>(accum, out);
  } else {
    float* invn  = (float*)d_ws;
    float* accum = (float*)((char*)d_ws + NROWS * sizeof(float));
    prep_kernel<1><<<NROWS, 256, 0, stream>>>(in, nullptr, invn, accum);
    tri_gemm_fly<<<NBLK, 256, 0, stream>>>(in, invn, accum);
    finalize_kernel<<<1, 64, 0, stream>>>(accum, out);
  }
}